// Round 1
// baseline (3907.884 us; speedup 1.0000x reference)
//
#include <hip/hip_runtime.h>
#include <math.h>

// ---------------------------------------------------------------------------
// STDF network forward: 2D U-Net branch + 3D temporal branch + offset/mask head
// + modulated deformable conv. All fp32 direct kernels (round 1: correctness).
// ---------------------------------------------------------------------------

#define TPB 256

// Generic 3x3 conv2d, NCHW, pad=1, runtime stride, optional relu.
__global__ void conv2d_k(const float* __restrict__ in, const float* __restrict__ w,
                         const float* __restrict__ bias, float* __restrict__ out,
                         int B, int Ci, int Hi, int Wi, int Co, int Ho, int Wo,
                         int stride, int do_relu) {
    int idx = blockIdx.x * blockDim.x + threadIdx.x;
    int total = B * Co * Ho * Wo;
    if (idx >= total) return;
    int wo = idx % Wo; int t = idx / Wo;
    int ho = t % Ho;   t /= Ho;
    int co = t % Co;   int b = t / Co;
    float acc = bias[co];
    int hbase = ho * stride - 1, wbase = wo * stride - 1;
    const float* wp = w + (size_t)co * Ci * 9;
    for (int ci = 0; ci < Ci; ++ci) {
        const float* ip = in + ((size_t)(b * Ci + ci)) * Hi * Wi;
        const float* wc = wp + ci * 9;
#pragma unroll
        for (int kh = 0; kh < 3; ++kh) {
            int y = hbase + kh;
            if (y < 0 || y >= Hi) continue;
            const float* row = ip + (size_t)y * Wi;
#pragma unroll
            for (int kw = 0; kw < 3; ++kw) {
                int x = wbase + kw;
                if (x < 0 || x >= Wi) continue;
                acc += row[x] * wc[kh * 3 + kw];
            }
        }
    }
    if (do_relu) acc = fmaxf(acc, 0.f);
    out[idx] = acc;
}

// 3x3 conv2d over virtual concat([in1(C1), in2(C2)]), stride 1, pad 1, relu.
__global__ void conv2d_cat_k(const float* __restrict__ in1, const float* __restrict__ in2,
                             const float* __restrict__ w, const float* __restrict__ bias,
                             float* __restrict__ out,
                             int B, int C1, int C2, int Hi, int Wi, int Co) {
    int idx = blockIdx.x * blockDim.x + threadIdx.x;
    int total = B * Co * Hi * Wi;
    if (idx >= total) return;
    int wo = idx % Wi; int t = idx / Wi;
    int ho = t % Hi;   t /= Hi;
    int co = t % Co;   int b = t / Co;
    int Ci = C1 + C2;
    float acc = bias[co];
    const float* wp = w + (size_t)co * Ci * 9;
    for (int ci = 0; ci < Ci; ++ci) {
        const float* ip = (ci < C1)
            ? in1 + ((size_t)(b * C1 + ci)) * Hi * Wi
            : in2 + ((size_t)(b * C2 + (ci - C1))) * Hi * Wi;
        const float* wc = wp + ci * 9;
#pragma unroll
        for (int kh = 0; kh < 3; ++kh) {
            int y = ho - 1 + kh;
            if (y < 0 || y >= Hi) continue;
            const float* row = ip + (size_t)y * Wi;
#pragma unroll
            for (int kw = 0; kw < 3; ++kw) {
                int x = wo - 1 + kw;
                if (x < 0 || x >= Wi) continue;
                acc += row[x] * wc[kh * 3 + kw];
            }
        }
    }
    out[idx] = fmaxf(acc, 0.f);
}

// Transposed conv 4x4, stride 2, pad 1 (JAX lhs_dilation=2 pad=2 with flipped wt).
// wt layout: (Cin, Cout, 4, 4). Output (B, C, 2Hi, 2Wi). relu always.
__global__ void convt2d_k(const float* __restrict__ in, const float* __restrict__ wt,
                          const float* __restrict__ bias, float* __restrict__ out,
                          int B, int C, int Hi, int Wi) {
    int Ho = 2 * Hi, Wo = 2 * Wi;
    int idx = blockIdx.x * blockDim.x + threadIdx.x;
    int total = B * C * Ho * Wo;
    if (idx >= total) return;
    int wo = idx % Wo; int t = idx / Wo;
    int ho = t % Ho;   t /= Ho;
    int co = t % C;    int b = t / C;
    float acc = bias[co];
#pragma unroll
    for (int kh = 0; kh < 4; ++kh) {
        int p = ho + kh - 2;
        if (p < 0 || p >= 2 * Hi || (p & 1)) continue;
        int iy = p >> 1;
#pragma unroll
        for (int kw = 0; kw < 4; ++kw) {
            int q = wo + kw - 2;
            if (q < 0 || q >= 2 * Wi || (q & 1)) continue;
            int ix = q >> 1;
            const float* ip = in + ((size_t)b * C * Hi + iy) * Wi + ix;
            const float* wp = wt + (size_t)co * 16 + (3 - kh) * 4 + (3 - kw);
            for (int ci = 0; ci < C; ++ci)
                acc += ip[(size_t)ci * Hi * Wi] * wp[(size_t)ci * C * 16];
        }
    }
    out[idx] = fmaxf(acc, 0.f);
}

// conv3d #1: input (B,7,H,W) viewed as (B,1,7,H,W); w (32,1,3,3,3); pad 1; relu.
// out: (B,32,7,H,W)
__global__ void conv3d_a_k(const float* __restrict__ x, const float* __restrict__ w,
                           const float* __restrict__ bias, float* __restrict__ out,
                           int B, int H, int W) {
    int idx = blockIdx.x * blockDim.x + threadIdx.x;
    int total = B * 32 * 7 * H * W;
    if (idx >= total) return;
    int wq = idx % W; int t = idx / W;
    int hq = t % H;   t /= H;
    int d  = t % 7;   t /= 7;
    int co = t % 32;  int b = t / 32;
    float acc = bias[co];
    const float* wp = w + co * 27;
#pragma unroll
    for (int kd = 0; kd < 3; ++kd) {
        int dd = d + kd - 1;
        if (dd < 0 || dd >= 7) continue;
        const float* xp = x + ((size_t)(b * 7 + dd)) * H * W;
#pragma unroll
        for (int kh = 0; kh < 3; ++kh) {
            int y = hq + kh - 1;
            if (y < 0 || y >= H) continue;
            const float* row = xp + (size_t)y * W;
#pragma unroll
            for (int kw = 0; kw < 3; ++kw) {
                int xx = wq + kw - 1;
                if (xx < 0 || xx >= W) continue;
                acc += row[xx] * wp[kd * 9 + kh * 3 + kw];
            }
        }
    }
    out[idx] = fmaxf(acc, 0.f);
}

// conv3d #2 fused with relu + mean over depth.
// xa: (B,32,7,H,W); w (32,32,3,3,3); out (B,32,H,W) = mean_d relu(conv3d+b)
__global__ void conv3d_b_mean_k(const float* __restrict__ xa, const float* __restrict__ w,
                                const float* __restrict__ bias, float* __restrict__ out,
                                int B, int H, int W) {
    int idx = blockIdx.x * blockDim.x + threadIdx.x;
    int total = B * 32 * H * W;
    if (idx >= total) return;
    int wq = idx % W; int t = idx / W;
    int hq = t % H;   t /= H;
    int co = t % 32;  int b = t / 32;
    float accd[7];
#pragma unroll
    for (int d = 0; d < 7; ++d) accd[d] = bias[co];
    for (int ci = 0; ci < 32; ++ci) {
        const float* xp = xa + ((size_t)((b * 32 + ci) * 7)) * H * W;
        const float* wp = w + ((size_t)(co * 32 + ci)) * 27;
#pragma unroll
        for (int kd = 0; kd < 3; ++kd) {
#pragma unroll
            for (int kh = 0; kh < 3; ++kh) {
                int y = hq + kh - 1;
                if (y < 0 || y >= H) continue;
#pragma unroll
                for (int kw = 0; kw < 3; ++kw) {
                    int xx = wq + kw - 1;
                    if (xx < 0 || xx >= W) continue;
                    float wv = wp[kd * 9 + kh * 3 + kw];
                    const float* col = xp + (size_t)y * W + xx;
#pragma unroll
                    for (int d = 0; d < 7; ++d) {
                        int dd = d + kd - 1;
                        if (dd < 0 || dd >= 7) continue;
                        accd[d] += col[(size_t)dd * H * W] * wv;
                    }
                }
            }
        }
    }
    float m = 0.f;
#pragma unroll
    for (int d = 0; d < 7; ++d) m += fmaxf(accd[d], 0.f);
    out[idx] = m * (1.f / 7.f);
}

// fused = relu(t + tf), in place on t.
__global__ void add_relu_k(float* __restrict__ a, const float* __restrict__ b, int n) {
    int i = blockIdx.x * blockDim.x + threadIdx.x;
    if (i < n) a[i] = fmaxf(a[i] + b[i], 0.f);
}

// Modulated deformable conv 3x3: x (B,7,H,W), om (B,189,H,W) [126 offsets + 63 mask logits],
// w (64,7,3,3), bias (64). out (B,64,H,W), relu.
__global__ __launch_bounds__(TPB) void deform_conv_k(
    const float* __restrict__ x, const float* __restrict__ om,
    const float* __restrict__ w, const float* __restrict__ bias,
    float* __restrict__ out, int B, int H, int W) {
    __shared__ float lw[64 * 63];
    for (int i = threadIdx.x; i < 64 * 63; i += blockDim.x) lw[i] = w[i];
    __syncthreads();
    int idx = blockIdx.x * blockDim.x + threadIdx.x;
    int total = B * H * W;
    if (idx >= total) return;
    int wq = idx % W; int t = idx / W;
    int hq = t % H;   int b = t / H;
    float acc[64];
#pragma unroll
    for (int o = 0; o < 64; ++o) acc[o] = 0.f;
    const size_t HW = (size_t)H * W;
    const float* omb = om + (size_t)b * 189 * HW;
    size_t hw = (size_t)hq * W + wq;
    for (int c = 0; c < 7; ++c) {
        const float* xc = x + ((size_t)(b * 7 + c)) * HW;
#pragma unroll
        for (int k = 0; k < 9; ++k) {
            float dy = omb[(size_t)(c * 18 + k * 2 + 0) * HW + hw];
            float dx = omb[(size_t)(c * 18 + k * 2 + 1) * HW + hw];
            float mv = omb[(size_t)(126 + c * 9 + k) * HW + hw];
            float m = 1.f / (1.f + __expf(-mv));
            float py = (float)hq + (float)(k / 3 - 1) + dy;
            float px = (float)wq + (float)(k % 3 - 1) + dx;
            float y0f = floorf(py), x0f = floorf(px);
            int y0 = (int)y0f, x0 = (int)x0f;
            float wy1 = py - y0f, wx1 = px - x0f;
            float wy0 = 1.f - wy1, wx0 = 1.f - wx1;
            float v00 = 0.f, v01 = 0.f, v10 = 0.f, v11 = 0.f;
            bool yin0 = (y0 >= 0) & (y0 < H);
            bool yin1 = (y0 + 1 >= 0) & (y0 + 1 < H);
            bool xin0 = (x0 >= 0) & (x0 < W);
            bool xin1 = (x0 + 1 >= 0) & (x0 + 1 < W);
            if (yin0) {
                const float* r = xc + (size_t)y0 * W;
                if (xin0) v00 = r[x0];
                if (xin1) v01 = r[x0 + 1];
            }
            if (yin1) {
                const float* r = xc + (size_t)(y0 + 1) * W;
                if (xin0) v10 = r[x0];
                if (xin1) v11 = r[x0 + 1];
            }
            float s = (wy0 * wx0 * v00 + wy0 * wx1 * v01 + wy1 * wx0 * v10 + wy1 * wx1 * v11) * m;
            int ck = c * 9 + k;
#pragma unroll
            for (int o = 0; o < 64; ++o) acc[o] += s * lw[o * 63 + ck];
        }
    }
    size_t obase = (size_t)b * 64 * HW + hw;
#pragma unroll
    for (int o = 0; o < 64; ++o)
        out[obase + (size_t)o * HW] = fmaxf(acc[o] + bias[o], 0.f);
}

static inline int nblk(long long total) { return (int)((total + TPB - 1) / TPB); }

extern "C" void kernel_launch(void* const* d_in, const int* in_sizes, int n_in,
                              void* d_out, int out_size, void* d_ws, size_t ws_size,
                              hipStream_t stream) {
    (void)in_sizes; (void)n_in; (void)out_size; (void)ws_size;
    const float* inputs = (const float*)d_in[0];
    const float* w_in   = (const float*)d_in[1];  const float* b_in   = (const float*)d_in[2];
    const float* w_dn1a = (const float*)d_in[3];  const float* b_dn1a = (const float*)d_in[4];
    const float* w_dn1b = (const float*)d_in[5];  const float* b_dn1b = (const float*)d_in[6];
    const float* w_up1a = (const float*)d_in[7];  const float* b_up1a = (const float*)d_in[8];
    const float* wt_up1 = (const float*)d_in[9];  const float* bt_up1 = (const float*)d_in[10];
    const float* w_dn2a = (const float*)d_in[11]; const float* b_dn2a = (const float*)d_in[12];
    const float* w_dn2b = (const float*)d_in[13]; const float* b_dn2b = (const float*)d_in[14];
    const float* w_up2a = (const float*)d_in[15]; const float* b_up2a = (const float*)d_in[16];
    const float* wt_up2 = (const float*)d_in[17]; const float* bt_up2 = (const float*)d_in[18];
    const float* w_tra  = (const float*)d_in[19]; const float* b_tra  = (const float*)d_in[20];
    const float* w_trb  = (const float*)d_in[21]; const float* b_trb  = (const float*)d_in[22];
    const float* wt_tr  = (const float*)d_in[23]; const float* bt_tr  = (const float*)d_in[24];
    const float* w_out  = (const float*)d_in[25]; const float* b_out  = (const float*)d_in[26];
    const float* w_tf3a = (const float*)d_in[27]; const float* b_tf3a = (const float*)d_in[28];
    const float* w_tf3b = (const float*)d_in[29]; const float* b_tf3b = (const float*)d_in[30];
    const float* w_tf2  = (const float*)d_in[31]; const float* b_tf2  = (const float*)d_in[32];
    const float* w_om   = (const float*)d_in[33]; const float* b_om   = (const float*)d_in[34];
    const float* w_dc   = (const float*)d_in[35]; const float* b_dc   = (const float*)d_in[36];
    float* out = (float*)d_out;

    const int B = 2, nf = 32, H = 160, W = 160;
    const size_t n160 = (size_t)B * nf * 160 * 160;  // 1,638,400
    const size_t n80  = (size_t)B * nf * 80 * 80;    //   409,600
    const size_t n40  = (size_t)B * nf * 40 * 40;    //   102,400
    const size_t n20  = (size_t)B * nf * 20 * 20;    //    25,600

    float* ws = (float*)d_ws;
    float* F0    = ws;                 // 1,638,400  (reused as MEAN)
    float* TMP80 = F0 + n160;
    float* F1    = TMP80 + n80;
    float* TMP40 = F1 + n80;
    float* F2    = TMP40 + n40;
    float* T20A  = F2 + n40;
    float* T20B  = T20A + n20;
    float* T40   = T20B + n20;
    float* T40B  = T40 + n40;
    float* T80   = T40B + n40;
    float* T80B  = T80 + n80;
    float* T160  = T80B + n80;         // reused as FUSED (in-place add)
    float* TF    = T160 + n160;        // reused as OUTC
    float* X3A   = TF + n160;          // 11,468,800
    float* OM    = X3A + (size_t)B * 32 * 7 * 160 * 160;  // 9,676,800

    // --- 2D U-Net branch ---
    conv2d_k<<<nblk(n160), TPB, 0, stream>>>(inputs, w_in, b_in, F0, B, 7, 160, 160, nf, 160, 160, 1, 1);
    conv2d_k<<<nblk(n80), TPB, 0, stream>>>(F0, w_dn1a, b_dn1a, TMP80, B, nf, 160, 160, nf, 80, 80, 2, 1);
    conv2d_k<<<nblk(n80), TPB, 0, stream>>>(TMP80, w_dn1b, b_dn1b, F1, B, nf, 80, 80, nf, 80, 80, 1, 1);
    conv2d_k<<<nblk(n40), TPB, 0, stream>>>(F1, w_dn2a, b_dn2a, TMP40, B, nf, 80, 80, nf, 40, 40, 2, 1);
    conv2d_k<<<nblk(n40), TPB, 0, stream>>>(TMP40, w_dn2b, b_dn2b, F2, B, nf, 40, 40, nf, 40, 40, 1, 1);
    conv2d_k<<<nblk(n20), TPB, 0, stream>>>(F2, w_tra, b_tra, T20A, B, nf, 40, 40, nf, 20, 20, 2, 1);
    conv2d_k<<<nblk(n20), TPB, 0, stream>>>(T20A, w_trb, b_trb, T20B, B, nf, 20, 20, nf, 20, 20, 1, 1);
    convt2d_k<<<nblk(n40), TPB, 0, stream>>>(T20B, wt_tr, bt_tr, T40, B, nf, 20, 20);
    conv2d_cat_k<<<nblk(n40), TPB, 0, stream>>>(T40, F2, w_up2a, b_up2a, T40B, B, nf, nf, 40, 40, nf);
    convt2d_k<<<nblk(n80), TPB, 0, stream>>>(T40B, wt_up2, bt_up2, T80, B, nf, 40, 40);
    conv2d_cat_k<<<nblk(n80), TPB, 0, stream>>>(T80, F1, w_up1a, b_up1a, T80B, B, nf, nf, 80, 80, nf);
    convt2d_k<<<nblk(n160), TPB, 0, stream>>>(T80B, wt_up1, bt_up1, T160, B, nf, 80, 80);

    // --- 3D temporal branch ---
    conv3d_a_k<<<nblk((long long)B * 32 * 7 * H * W), TPB, 0, stream>>>(inputs, w_tf3a, b_tf3a, X3A, B, H, W);
    conv3d_b_mean_k<<<nblk(n160), TPB, 0, stream>>>(X3A, w_tf3b, b_tf3b, F0, B, H, W);  // MEAN -> F0
    conv2d_k<<<nblk(n160), TPB, 0, stream>>>(F0, w_tf2, b_tf2, TF, B, nf, 160, 160, nf, 160, 160, 1, 0);

    // --- fuse + offset/mask head ---
    add_relu_k<<<nblk(n160), TPB, 0, stream>>>(T160, TF, (int)n160);                     // FUSED in T160
    conv2d_k<<<nblk(n160), TPB, 0, stream>>>(T160, w_out, b_out, TF, B, nf, 160, 160, nf, 160, 160, 1, 1); // OUTC -> TF
    conv2d_k<<<nblk((long long)B * 189 * H * W), TPB, 0, stream>>>(TF, w_om, b_om, OM, B, nf, 160, 160, 189, 160, 160, 1, 0);

    // --- deformable conv ---
    deform_conv_k<<<nblk((long long)B * H * W), TPB, 0, stream>>>(inputs, OM, w_dc, b_dc, out, B, H, W);
}

// Round 2
// 2103.779 us; speedup vs baseline: 1.8576x; 1.8576x over previous
//
#include <hip/hip_runtime.h>
#include <math.h>

// ---------------------------------------------------------------------------
// STDF forward, round 2: LDS-tiled fused conv3d branch, 4-wide register-tiled
// conv2d family with block-uniform co + LDS weights, improved deform conv.
// ---------------------------------------------------------------------------

#define TPB 256

static inline int nblk(long long total) { return (int)((total + TPB - 1) / TPB); }
static inline int bpc_of(int H, int nq) { return (H * nq + TPB - 1) / TPB; }

// ---------------- 3x3 conv2d, stride 1, 4 outputs/thread, block-uniform co --
// grid.x = B * Co * BPC ; BPC = ceil(H*(W/4)/256)
template <int RELU, int HAS_RES>
__global__ __launch_bounds__(TPB) void conv2d_t4_k(
    const float* __restrict__ in, const float* __restrict__ w,
    const float* __restrict__ bias, const float* __restrict__ res,
    float* __restrict__ out, int B, int Ci, int H, int W, int Co, int BPC) {
    __shared__ float ws_w[32 * 9];
    int co = (blockIdx.x / BPC) % Co;
    int b  = blockIdx.x / (BPC * Co);
    for (int i = threadIdx.x; i < Ci * 9; i += TPB)
        ws_w[i] = w[(size_t)co * Ci * 9 + i];
    __syncthreads();
    int nq = W >> 2;
    int r = (blockIdx.x % BPC) * TPB + threadIdx.x;
    if (r >= H * nq) return;
    int q = r % nq, ho = r / nq;
    int wb = q * 4;
    float bv = bias[co];
    float a0 = bv, a1 = bv, a2 = bv, a3 = bv;
    const float* ipb = in + (size_t)b * Ci * H * W;
    for (int ci = 0; ci < Ci; ++ci) {
        const float* ip = ipb + (size_t)ci * H * W;
        const float* wc = ws_w + ci * 9;
#pragma unroll
        for (int kh = 0; kh < 3; ++kh) {
            int y = ho - 1 + kh;
            if (y < 0 || y >= H) continue;
            const float* row = ip + (size_t)y * W + wb;
            float4 xv = *(const float4*)row;
            float xm = (wb > 0) ? row[-1] : 0.f;
            float xp = (wb + 4 < W) ? row[4] : 0.f;
            float w0 = wc[kh * 3], w1 = wc[kh * 3 + 1], w2 = wc[kh * 3 + 2];
            a0 += xm   * w0 + xv.x * w1 + xv.y * w2;
            a1 += xv.x * w0 + xv.y * w1 + xv.z * w2;
            a2 += xv.y * w0 + xv.z * w1 + xv.w * w2;
            a3 += xv.z * w0 + xv.w * w1 + xp   * w2;
        }
    }
    size_t o = ((size_t)(b * Co + co) * H + ho) * W + wb;
    if (HAS_RES) {
        float4 rv = *(const float4*)(res + o);
        a0 += rv.x; a1 += rv.y; a2 += rv.z; a3 += rv.w;
    }
    if (RELU) { a0 = fmaxf(a0, 0.f); a1 = fmaxf(a1, 0.f); a2 = fmaxf(a2, 0.f); a3 = fmaxf(a3, 0.f); }
    float4 ov = make_float4(a0, a1, a2, a3);
    *(float4*)(out + o) = ov;
}

// ------------- 3x3 conv2d over concat of two 32-ch inputs, stride 1, relu ---
__global__ __launch_bounds__(TPB) void conv2d_cat_t4_k(
    const float* __restrict__ in1, const float* __restrict__ in2,
    const float* __restrict__ w, const float* __restrict__ bias,
    float* __restrict__ out, int B, int C1, int C2, int H, int W, int Co, int BPC) {
    __shared__ float ws_w[64 * 9];
    int Ci = C1 + C2;
    int co = (blockIdx.x / BPC) % Co;
    int b  = blockIdx.x / (BPC * Co);
    for (int i = threadIdx.x; i < Ci * 9; i += TPB)
        ws_w[i] = w[(size_t)co * Ci * 9 + i];
    __syncthreads();
    int nq = W >> 2;
    int r = (blockIdx.x % BPC) * TPB + threadIdx.x;
    if (r >= H * nq) return;
    int q = r % nq, ho = r / nq;
    int wb = q * 4;
    float bv = bias[co];
    float a0 = bv, a1 = bv, a2 = bv, a3 = bv;
    for (int ci = 0; ci < Ci; ++ci) {
        const float* ip = (ci < C1)
            ? in1 + ((size_t)(b * C1 + ci)) * H * W
            : in2 + ((size_t)(b * C2 + (ci - C1))) * H * W;
        const float* wc = ws_w + ci * 9;
#pragma unroll
        for (int kh = 0; kh < 3; ++kh) {
            int y = ho - 1 + kh;
            if (y < 0 || y >= H) continue;
            const float* row = ip + (size_t)y * W + wb;
            float4 xv = *(const float4*)row;
            float xm = (wb > 0) ? row[-1] : 0.f;
            float xp = (wb + 4 < W) ? row[4] : 0.f;
            float w0 = wc[kh * 3], w1 = wc[kh * 3 + 1], w2 = wc[kh * 3 + 2];
            a0 += xm   * w0 + xv.x * w1 + xv.y * w2;
            a1 += xv.x * w0 + xv.y * w1 + xv.z * w2;
            a2 += xv.y * w0 + xv.z * w1 + xv.w * w2;
            a3 += xv.z * w0 + xv.w * w1 + xp   * w2;
        }
    }
    size_t o = ((size_t)(b * Co + co) * H + ho) * W + wb;
    float4 ov = make_float4(fmaxf(a0, 0.f), fmaxf(a1, 0.f), fmaxf(a2, 0.f), fmaxf(a3, 0.f));
    *(float4*)(out + o) = ov;
}

// ------------- 3x3 conv2d, stride 2, 4 outputs/thread, relu ----------------
// in: (B,Ci,Hi,Wi) -> out: (B,Co,Hi/2,Wi/2)
__global__ __launch_bounds__(TPB) void conv2d_s2_t4_k(
    const float* __restrict__ in, const float* __restrict__ w,
    const float* __restrict__ bias, float* __restrict__ out,
    int B, int Ci, int Hi, int Wi, int Co, int BPC) {
    __shared__ float ws_w[32 * 9];
    int Ho = Hi >> 1, Wo = Wi >> 1;
    int co = (blockIdx.x / BPC) % Co;
    int b  = blockIdx.x / (BPC * Co);
    for (int i = threadIdx.x; i < Ci * 9; i += TPB)
        ws_w[i] = w[(size_t)co * Ci * 9 + i];
    __syncthreads();
    int nq = Wo >> 2;
    int r = (blockIdx.x % BPC) * TPB + threadIdx.x;
    if (r >= Ho * nq) return;
    int q = r % nq, ho = r / nq;
    int wb = q * 4;               // output col base; input col base 2*wb-1
    float bv = bias[co];
    float a0 = bv, a1 = bv, a2 = bv, a3 = bv;
    const float* ipb = in + (size_t)b * Ci * Hi * Wi;
    for (int ci = 0; ci < Ci; ++ci) {
        const float* ip = ipb + (size_t)ci * Hi * Wi;
        const float* wc = ws_w + ci * 9;
#pragma unroll
        for (int kh = 0; kh < 3; ++kh) {
            int y = 2 * ho - 1 + kh;
            if (y < 0 || y >= Hi) continue;
            const float* row = ip + (size_t)y * Wi;
            float z0 = (2 * wb - 1 >= 0) ? row[2 * wb - 1] : 0.f;
            float4 za = *(const float4*)(row + 2 * wb);
            float4 zb = *(const float4*)(row + 2 * wb + 4);
            float w0 = wc[kh * 3], w1 = wc[kh * 3 + 1], w2 = wc[kh * 3 + 2];
            a0 += z0   * w0 + za.x * w1 + za.y * w2;
            a1 += za.y * w0 + za.z * w1 + za.w * w2;
            a2 += za.w * w0 + zb.x * w1 + zb.y * w2;
            a3 += zb.y * w0 + zb.z * w1 + zb.w * w2;
        }
    }
    size_t o = ((size_t)(b * Co + co) * Ho + ho) * Wo + wb;
    float4 ov = make_float4(fmaxf(a0, 0.f), fmaxf(a1, 0.f), fmaxf(a2, 0.f), fmaxf(a3, 0.f));
    *(float4*)(out + o) = ov;
}

// ------------- transposed conv 4x4 stride 2, 4 outputs/thread, relu --------
// in: (B,C,Hi,Wi), wt: (C,C,4,4), out: (B,C,2Hi,2Wi)
__global__ __launch_bounds__(TPB) void convt2d_t4_k(
    const float* __restrict__ in, const float* __restrict__ wt,
    const float* __restrict__ bias, float* __restrict__ out,
    int B, int C, int Hi, int Wi, int BPC) {
    __shared__ float ws_w[32 * 16];   // wt[ci][co][4][4] for this co
    int Ho = 2 * Hi, Wo = 2 * Wi;
    int co = (blockIdx.x / BPC) % C;
    int b  = blockIdx.x / (BPC * C);
    for (int i = threadIdx.x; i < C * 16; i += TPB) {
        int ci = i >> 4, t = i & 15;
        ws_w[i] = wt[((size_t)ci * C + co) * 16 + t];
    }
    __syncthreads();
    int nq = Wo >> 2;
    int r = (blockIdx.x % BPC) * TPB + threadIdx.x;
    if (r >= Ho * nq) return;
    int q = r % nq, ho = r / nq;
    int wb = q * 4;
    int p = ho & 1;                       // kh parity
    int iy0 = (ho + p) / 2 - 1;           // for kh = p
    int iy1 = iy0 + 1;                    // for kh = p+2
    int ix0 = wb / 2 - 1;                 // 4 consecutive input cols ix0..ix0+3
    bool vy0 = (iy0 >= 0) && (iy0 < Hi);
    bool vy1 = (iy1 >= 0) && (iy1 < Hi);
    float bv = bias[co];
    float a0 = bv, a1 = bv, a2 = bv, a3 = bv;
    const float* ipb = in + (size_t)b * C * Hi * Wi;
    for (int ci = 0; ci < C; ++ci) {
        const float* ip = ipb + (size_t)ci * Hi * Wi;
        float u0 = 0, u1 = 0, u2 = 0, u3 = 0, v0 = 0, v1 = 0, v2 = 0, v3 = 0;
        if (vy0) {
            const float* rw = ip + (size_t)iy0 * Wi;
            if (ix0 >= 0) u0 = rw[ix0];
            u1 = rw[ix0 + 1]; u2 = rw[ix0 + 2];
            if (ix0 + 3 < Wi) u3 = rw[ix0 + 3];
        }
        if (vy1) {
            const float* rw = ip + (size_t)iy1 * Wi;
            if (ix0 >= 0) v0 = rw[ix0];
            v1 = rw[ix0 + 1]; v2 = rw[ix0 + 2];
            if (ix0 + 3 < Wi) v3 = rw[ix0 + 3];
        }
        const float* wr0 = ws_w + ci * 16 + (3 - p) * 4;  // kh = p
        const float* wr1 = ws_w + ci * 16 + (1 - p) * 4;  // kh = p+2
        a0 += u0 * wr0[3] + u1 * wr0[1] + v0 * wr1[3] + v1 * wr1[1];
        a1 += u1 * wr0[2] + u2 * wr0[0] + v1 * wr1[2] + v2 * wr1[0];
        a2 += u1 * wr0[3] + u2 * wr0[1] + v1 * wr1[3] + v2 * wr1[1];
        a3 += u2 * wr0[2] + u3 * wr0[0] + v2 * wr1[2] + v3 * wr1[0];
    }
    size_t o = ((size_t)(b * C + co) * Ho + ho) * Wo + wb;
    float4 ov = make_float4(fmaxf(a0, 0.f), fmaxf(a1, 0.f), fmaxf(a2, 0.f), fmaxf(a3, 0.f));
    *(float4*)(out + o) = ov;
}

// ------------- fused 3D branch: conv3d_a + relu + conv3d_b + relu + mean ----
// x: (B,7,H,W); wa: (32,1,3,3,3); wb: (32,32,3,3,3); out: (B,32,H,W)
// block: 256 = 64 pixels (8x8) x 4 co-groups of 8; grid: B*(H/8)*(W/8)
__global__ __launch_bounds__(TPB) void conv3d_fused_k(
    const float* __restrict__ x, const float* __restrict__ wa,
    const float* __restrict__ ba, const float* __restrict__ wbg,
    const float* __restrict__ bb, float* __restrict__ out,
    int B, int H, int W) {
    __shared__ float xin[7][12][12];   // raw input tile (halo 2)
    __shared__ float xa[7][10][10];    // conv3d_a output tile for current ci (halo 1)
    __shared__ float wsa[32 * 27];
    __shared__ float wsb[32 * 27];
    int nbx = W / 8;
    int blk = blockIdx.x;
    int bx = blk % nbx; int by = (blk / nbx) % (H / 8); int b = blk / (nbx * (H / 8));
    int h0 = by * 8, w0 = bx * 8;
    int tid = threadIdx.x;

    for (int i = tid; i < 7 * 12 * 12; i += TPB) {
        int xx = i % 12; int yy = (i / 12) % 12; int dd = i / 144;
        int gy = h0 - 2 + yy, gx = w0 - 2 + xx;
        float v = 0.f;
        if (gy >= 0 && gy < H && gx >= 0 && gx < W)
            v = x[((size_t)(b * 7 + dd)) * H * W + (size_t)gy * W + gx];
        (&xin[0][0][0])[i] = v;
    }
    for (int i = tid; i < 32 * 27; i += TPB) wsa[i] = wa[i];

    int p = tid & 63; int px = p & 7; int py = p >> 3;
    int g = tid >> 6; int cob = g * 8;

    float acc[8][7];
#pragma unroll
    for (int r = 0; r < 8; ++r) {
        float bv = bb[cob + r];
#pragma unroll
        for (int d = 0; d < 7; ++d) acc[r][d] = bv;
    }
    __syncthreads();

    for (int ci = 0; ci < 32; ++ci) {
        // stage b-weights for this ci
        for (int i = tid; i < 32 * 27; i += TPB) {
            int co = i / 27, j = i % 27;
            wsb[i] = wbg[((size_t)co * 32 + ci) * 27 + j];
        }
        // compute conv3d_a tile (with relu) for this ci
        float bci = ba[ci];
        const float* wv = wsa + ci * 27;
        for (int i = tid; i < 7 * 10 * 10; i += TPB) {
            int xx = i % 10; int t2 = i / 10; int yy = t2 % 10; int dd = t2 / 10;
            float a = bci;
#pragma unroll
            for (int kd = 0; kd < 3; ++kd) {
                int dz = dd + kd - 1;
                if (dz < 0 || dz >= 7) continue;
#pragma unroll
                for (int kh = 0; kh < 3; ++kh)
#pragma unroll
                    for (int kw = 0; kw < 3; ++kw)
                        a += xin[dz][yy + kh][xx + kw] * wv[kd * 9 + kh * 3 + kw];
            }
            (&xa[0][0][0])[i] = fmaxf(a, 0.f);
        }
        __syncthreads();
        // main accumulate
#pragma unroll
        for (int dd = 0; dd < 7; ++dd) {
#pragma unroll
            for (int kh = 0; kh < 3; ++kh) {
#pragma unroll
                for (int kw = 0; kw < 3; ++kw) {
                    float v = xa[dd][py + kh][px + kw];
#pragma unroll
                    for (int r = 0; r < 8; ++r) {
                        const float* wp = wsb + (cob + r) * 27 + kh * 3 + kw;
#pragma unroll
                        for (int kd = 0; kd < 3; ++kd) {
                            int d = dd + 1 - kd;
                            if (d >= 0 && d < 7)
                                acc[r][d] += v * wp[kd * 9];
                        }
                    }
                }
            }
        }
        __syncthreads();
    }
    size_t HW = (size_t)H * W;
#pragma unroll
    for (int r = 0; r < 8; ++r) {
        float s = 0.f;
#pragma unroll
        for (int d = 0; d < 7; ++d) s += fmaxf(acc[r][d], 0.f);
        out[((size_t)(b * 32 + cob + r)) * HW + (size_t)(h0 + py) * W + (w0 + px)] = s * (1.f / 7.f);
    }
}

// ------------- modulated deformable conv, 32 co per thread, 2 halves -------
__global__ __launch_bounds__(TPB) void deform_conv_k(
    const float* __restrict__ x, const float* __restrict__ om,
    const float* __restrict__ w, const float* __restrict__ bias,
    float* __restrict__ out, int B, int H, int W) {
    __shared__ float lwT[63 * 64];     // [ck][o]
    for (int i = threadIdx.x; i < 63 * 64; i += TPB) {
        int o = i & 63, ck = i >> 6;
        lwT[i] = w[o * 63 + ck];
    }
    __syncthreads();
    int ob = blockIdx.y * 32;
    int idx = blockIdx.x * blockDim.x + threadIdx.x;
    int total = B * H * W;
    if (idx >= total) return;
    int wq = idx % W; int t = idx / W;
    int hq = t % H;   int b = t / H;
    float acc[32];
#pragma unroll
    for (int o = 0; o < 32; ++o) acc[o] = 0.f;
    const size_t HW = (size_t)H * W;
    const float* omb = om + (size_t)b * 189 * HW;
    size_t hw = (size_t)hq * W + wq;
    for (int c = 0; c < 7; ++c) {
        const float* xc = x + ((size_t)(b * 7 + c)) * HW;
#pragma unroll
        for (int k = 0; k < 9; ++k) {
            float dy = omb[(size_t)(c * 18 + k * 2 + 0) * HW + hw];
            float dx = omb[(size_t)(c * 18 + k * 2 + 1) * HW + hw];
            float mv = omb[(size_t)(126 + c * 9 + k) * HW + hw];
            float m = 1.f / (1.f + __expf(-mv));
            float py = (float)hq + (float)(k / 3 - 1) + dy;
            float px = (float)wq + (float)(k % 3 - 1) + dx;
            float y0f = floorf(py), x0f = floorf(px);
            int y0 = (int)y0f, x0 = (int)x0f;
            float wy1 = py - y0f, wx1 = px - x0f;
            float wy0 = 1.f - wy1, wx0 = 1.f - wx1;
            float v00 = 0.f, v01 = 0.f, v10 = 0.f, v11 = 0.f;
            bool yin0 = (y0 >= 0) & (y0 < H);
            bool yin1 = (y0 + 1 >= 0) & (y0 + 1 < H);
            bool xin0 = (x0 >= 0) & (x0 < W);
            bool xin1 = (x0 + 1 >= 0) & (x0 + 1 < W);
            if (yin0) {
                const float* rr = xc + (size_t)y0 * W;
                if (xin0) v00 = rr[x0];
                if (xin1) v01 = rr[x0 + 1];
            }
            if (yin1) {
                const float* rr = xc + (size_t)(y0 + 1) * W;
                if (xin0) v10 = rr[x0];
                if (xin1) v11 = rr[x0 + 1];
            }
            float s = (wy0 * wx0 * v00 + wy0 * wx1 * v01 + wy1 * wx0 * v10 + wy1 * wx1 * v11) * m;
            int ck = c * 9 + k;
            const float* lp = lwT + ck * 64 + ob;
#pragma unroll
            for (int o = 0; o < 32; ++o) acc[o] += s * lp[o];
        }
    }
    size_t obase = (size_t)b * 64 * HW + hw;
#pragma unroll
    for (int o = 0; o < 32; ++o)
        out[obase + (size_t)(ob + o) * HW] = fmaxf(acc[o] + bias[ob + o], 0.f);
}

extern "C" void kernel_launch(void* const* d_in, const int* in_sizes, int n_in,
                              void* d_out, int out_size, void* d_ws, size_t ws_size,
                              hipStream_t stream) {
    (void)in_sizes; (void)n_in; (void)out_size; (void)ws_size;
    const float* inputs = (const float*)d_in[0];
    const float* w_in   = (const float*)d_in[1];  const float* b_in   = (const float*)d_in[2];
    const float* w_dn1a = (const float*)d_in[3];  const float* b_dn1a = (const float*)d_in[4];
    const float* w_dn1b = (const float*)d_in[5];  const float* b_dn1b = (const float*)d_in[6];
    const float* w_up1a = (const float*)d_in[7];  const float* b_up1a = (const float*)d_in[8];
    const float* wt_up1 = (const float*)d_in[9];  const float* bt_up1 = (const float*)d_in[10];
    const float* w_dn2a = (const float*)d_in[11]; const float* b_dn2a = (const float*)d_in[12];
    const float* w_dn2b = (const float*)d_in[13]; const float* b_dn2b = (const float*)d_in[14];
    const float* w_up2a = (const float*)d_in[15]; const float* b_up2a = (const float*)d_in[16];
    const float* wt_up2 = (const float*)d_in[17]; const float* bt_up2 = (const float*)d_in[18];
    const float* w_tra  = (const float*)d_in[19]; const float* b_tra  = (const float*)d_in[20];
    const float* w_trb  = (const float*)d_in[21]; const float* b_trb  = (const float*)d_in[22];
    const float* wt_tr  = (const float*)d_in[23]; const float* bt_tr  = (const float*)d_in[24];
    const float* w_out  = (const float*)d_in[25]; const float* b_out  = (const float*)d_in[26];
    const float* w_tf3a = (const float*)d_in[27]; const float* b_tf3a = (const float*)d_in[28];
    const float* w_tf3b = (const float*)d_in[29]; const float* b_tf3b = (const float*)d_in[30];
    const float* w_tf2  = (const float*)d_in[31]; const float* b_tf2  = (const float*)d_in[32];
    const float* w_om   = (const float*)d_in[33]; const float* b_om   = (const float*)d_in[34];
    const float* w_dc   = (const float*)d_in[35]; const float* b_dc   = (const float*)d_in[36];
    float* out = (float*)d_out;

    const int B = 2, nf = 32, H = 160, W = 160;
    const size_t n160 = (size_t)B * nf * 160 * 160;
    const size_t n80  = (size_t)B * nf * 80 * 80;
    const size_t n40  = (size_t)B * nf * 40 * 40;
    const size_t n20  = (size_t)B * nf * 20 * 20;

    float* ws = (float*)d_ws;
    float* F0    = ws;                 // also MEAN, later OUTC
    float* TMP80 = F0 + n160;
    float* F1    = TMP80 + n80;
    float* TMP40 = F1 + n80;
    float* F2    = TMP40 + n40;
    float* T20A  = F2 + n40;
    float* T20B  = T20A + n20;
    float* T40   = T20B + n20;
    float* T40B  = T40 + n40;
    float* T80   = T40B + n40;
    float* T80B  = T80 + n80;
    float* T160  = T80B + n80;         // U-Net output t
    float* TF    = T160 + n160;        // FUSED
    float* OM    = TF + n160;          // 9,676,800 floats

    const int bpc160 = bpc_of(160, 40);   // 25
    const int bpc80  = bpc_of(80, 20);    // 7
    const int bpc40  = bpc_of(40, 10);    // 2
    const int bpc20  = bpc_of(20, 5);     // 1

    // --- 2D U-Net branch ---
    conv2d_t4_k<1, 0><<<B * nf * bpc160, TPB, 0, stream>>>(inputs, w_in, b_in, nullptr, F0, B, 7, 160, 160, nf, bpc160);
    conv2d_s2_t4_k<<<B * nf * bpc80, TPB, 0, stream>>>(F0, w_dn1a, b_dn1a, TMP80, B, nf, 160, 160, nf, bpc80);
    conv2d_t4_k<1, 0><<<B * nf * bpc80, TPB, 0, stream>>>(TMP80, w_dn1b, b_dn1b, nullptr, F1, B, nf, 80, 80, nf, bpc80);
    conv2d_s2_t4_k<<<B * nf * bpc40, TPB, 0, stream>>>(F1, w_dn2a, b_dn2a, TMP40, B, nf, 80, 80, nf, bpc40);
    conv2d_t4_k<1, 0><<<B * nf * bpc40, TPB, 0, stream>>>(TMP40, w_dn2b, b_dn2b, nullptr, F2, B, nf, 40, 40, nf, bpc40);
    conv2d_s2_t4_k<<<B * nf * bpc20, TPB, 0, stream>>>(F2, w_tra, b_tra, T20A, B, nf, 40, 40, nf, bpc20);
    conv2d_t4_k<1, 0><<<B * nf * bpc20, TPB, 0, stream>>>(T20A, w_trb, b_trb, nullptr, T20B, B, nf, 20, 20, nf, bpc20);
    convt2d_t4_k<<<B * nf * bpc40, TPB, 0, stream>>>(T20B, wt_tr, bt_tr, T40, B, nf, 20, 20, bpc40);
    conv2d_cat_t4_k<<<B * nf * bpc40, TPB, 0, stream>>>(T40, F2, w_up2a, b_up2a, T40B, B, nf, nf, 40, 40, nf, bpc40);
    convt2d_t4_k<<<B * nf * bpc80, TPB, 0, stream>>>(T40B, wt_up2, bt_up2, T80, B, nf, 40, 40, bpc80);
    conv2d_cat_t4_k<<<B * nf * bpc80, TPB, 0, stream>>>(T80, F1, w_up1a, b_up1a, T80B, B, nf, nf, 80, 80, nf, bpc80);
    convt2d_t4_k<<<B * nf * bpc160, TPB, 0, stream>>>(T80B, wt_up1, bt_up1, T160, B, nf, 80, 80, bpc160);

    // --- 3D temporal branch (fully fused) ---
    conv3d_fused_k<<<B * (H / 8) * (W / 8), TPB, 0, stream>>>(inputs, w_tf3a, b_tf3a, w_tf3b, b_tf3b, F0, B, H, W);
    // FUSED = relu(conv_tf2(MEAN) + T160)
    conv2d_t4_k<1, 1><<<B * nf * bpc160, TPB, 0, stream>>>(F0, w_tf2, b_tf2, T160, TF, B, nf, 160, 160, nf, bpc160);

    // --- offset/mask head ---
    conv2d_t4_k<1, 0><<<B * nf * bpc160, TPB, 0, stream>>>(TF, w_out, b_out, nullptr, F0, B, nf, 160, 160, nf, bpc160);
    conv2d_t4_k<0, 0><<<B * 189 * bpc160, TPB, 0, stream>>>(F0, w_om, b_om, nullptr, OM, B, nf, 160, 160, 189, bpc160);

    // --- deformable conv ---
    dim3 dgrid(nblk((long long)B * H * W), 2);
    deform_conv_k<<<dgrid, TPB, 0, stream>>>(inputs, OM, w_dc, b_dc, out, B, H, W);
}

// Round 3
// 1187.178 us; speedup vs baseline: 3.2917x; 1.7721x over previous
//
#include <hip/hip_runtime.h>
#include <math.h>

// ---------------------------------------------------------------------------
// STDF forward, round 3: conv3d branch rebuilt (weights transposed in WS,
// 16co/block, double-buffered xa+weights, b128 weight reads), 4-co conv2d for
// the 160-level convs. Other kernels unchanged from the passing round-2 code.
// ---------------------------------------------------------------------------

#define TPB 256

static inline int nblk(long long total) { return (int)((total + TPB - 1) / TPB); }
static inline int bpc_of(int H, int nq) { return (H * nq + TPB - 1) / TPB; }

// ---------------- 3x3 conv2d, stride 1, 4 outputs/thread, block-uniform co --
template <int RELU, int HAS_RES>
__global__ __launch_bounds__(TPB) void conv2d_t4_k(
    const float* __restrict__ in, const float* __restrict__ w,
    const float* __restrict__ bias, const float* __restrict__ res,
    float* __restrict__ out, int B, int Ci, int H, int W, int Co, int BPC) {
    __shared__ float ws_w[32 * 9];
    int co = (blockIdx.x / BPC) % Co;
    int b  = blockIdx.x / (BPC * Co);
    for (int i = threadIdx.x; i < Ci * 9; i += TPB)
        ws_w[i] = w[(size_t)co * Ci * 9 + i];
    __syncthreads();
    int nq = W >> 2;
    int r = (blockIdx.x % BPC) * TPB + threadIdx.x;
    if (r >= H * nq) return;
    int q = r % nq, ho = r / nq;
    int wb = q * 4;
    float bv = bias[co];
    float a0 = bv, a1 = bv, a2 = bv, a3 = bv;
    const float* ipb = in + (size_t)b * Ci * H * W;
    for (int ci = 0; ci < Ci; ++ci) {
        const float* ip = ipb + (size_t)ci * H * W;
        const float* wc = ws_w + ci * 9;
#pragma unroll
        for (int kh = 0; kh < 3; ++kh) {
            int y = ho - 1 + kh;
            if (y < 0 || y >= H) continue;
            const float* row = ip + (size_t)y * W + wb;
            float4 xv = *(const float4*)row;
            float xm = (wb > 0) ? row[-1] : 0.f;
            float xp = (wb + 4 < W) ? row[4] : 0.f;
            float w0 = wc[kh * 3], w1 = wc[kh * 3 + 1], w2 = wc[kh * 3 + 2];
            a0 += xm   * w0 + xv.x * w1 + xv.y * w2;
            a1 += xv.x * w0 + xv.y * w1 + xv.z * w2;
            a2 += xv.y * w0 + xv.z * w1 + xv.w * w2;
            a3 += xv.z * w0 + xv.w * w1 + xp   * w2;
        }
    }
    size_t o = ((size_t)(b * Co + co) * H + ho) * W + wb;
    if (HAS_RES) {
        float4 rv = *(const float4*)(res + o);
        a0 += rv.x; a1 += rv.y; a2 += rv.z; a3 += rv.w;
    }
    if (RELU) { a0 = fmaxf(a0, 0.f); a1 = fmaxf(a1, 0.f); a2 = fmaxf(a2, 0.f); a3 = fmaxf(a3, 0.f); }
    *(float4*)(out + o) = make_float4(a0, a1, a2, a3);
}

// ------- 3x3 conv2d, stride 1, 4 outputs x 4 co per thread -----------------
// grid.x = B * COG * BPC, co group = 4 channels.
template <int RELU, int HAS_RES>
__global__ __launch_bounds__(TPB) void conv2d_c4_k(
    const float* __restrict__ in, const float* __restrict__ w,
    const float* __restrict__ bias, const float* __restrict__ res,
    float* __restrict__ out, int B, int Ci, int H, int W, int Co, int COG, int BPC) {
    __shared__ float ws_w[4 * 32 * 9];
    int cog = (blockIdx.x / BPC) % COG;
    int b   = blockIdx.x / (BPC * COG);
    int co0 = cog * 4;
    int nw = Ci * 9;
    for (int i = threadIdx.x; i < 4 * nw; i += TPB) {
        int cr = i / nw; int co = co0 + cr;
        ws_w[i] = (co < Co) ? w[(size_t)co * nw + (i - cr * nw)] : 0.f;
    }
    __syncthreads();
    int nq = W >> 2;
    int r = (blockIdx.x % BPC) * TPB + threadIdx.x;
    if (r >= H * nq) return;
    int q = r % nq, ho = r / nq;
    int wb = q * 4;
    float a[4][4];
#pragma unroll
    for (int cr = 0; cr < 4; ++cr) {
        float bv = (co0 + cr < Co) ? bias[co0 + cr] : 0.f;
        a[cr][0] = bv; a[cr][1] = bv; a[cr][2] = bv; a[cr][3] = bv;
    }
    const float* ipb = in + (size_t)b * Ci * H * W;
    for (int ci = 0; ci < Ci; ++ci) {
        const float* ip = ipb + (size_t)ci * H * W;
#pragma unroll
        for (int kh = 0; kh < 3; ++kh) {
            int y = ho - 1 + kh;
            if (y < 0 || y >= H) continue;
            const float* row = ip + (size_t)y * W + wb;
            float4 xv = *(const float4*)row;
            float xm = (wb > 0) ? row[-1] : 0.f;
            float xp = (wb + 4 < W) ? row[4] : 0.f;
#pragma unroll
            for (int cr = 0; cr < 4; ++cr) {
                const float* wc = ws_w + cr * nw + ci * 9 + kh * 3;
                float w0 = wc[0], w1 = wc[1], w2 = wc[2];
                a[cr][0] += xm   * w0 + xv.x * w1 + xv.y * w2;
                a[cr][1] += xv.x * w0 + xv.y * w1 + xv.z * w2;
                a[cr][2] += xv.y * w0 + xv.z * w1 + xv.w * w2;
                a[cr][3] += xv.z * w0 + xv.w * w1 + xp   * w2;
            }
        }
    }
#pragma unroll
    for (int cr = 0; cr < 4; ++cr) {
        int co = co0 + cr;
        if (co >= Co) break;
        size_t o = ((size_t)(b * Co + co) * H + ho) * W + wb;
        float a0 = a[cr][0], a1 = a[cr][1], a2 = a[cr][2], a3 = a[cr][3];
        if (HAS_RES) {
            float4 rv = *(const float4*)(res + o);
            a0 += rv.x; a1 += rv.y; a2 += rv.z; a3 += rv.w;
        }
        if (RELU) { a0 = fmaxf(a0, 0.f); a1 = fmaxf(a1, 0.f); a2 = fmaxf(a2, 0.f); a3 = fmaxf(a3, 0.f); }
        *(float4*)(out + o) = make_float4(a0, a1, a2, a3);
    }
}

// ------------- 3x3 conv2d over concat of two 32-ch inputs, stride 1, relu ---
__global__ __launch_bounds__(TPB) void conv2d_cat_t4_k(
    const float* __restrict__ in1, const float* __restrict__ in2,
    const float* __restrict__ w, const float* __restrict__ bias,
    float* __restrict__ out, int B, int C1, int C2, int H, int W, int Co, int BPC) {
    __shared__ float ws_w[64 * 9];
    int Ci = C1 + C2;
    int co = (blockIdx.x / BPC) % Co;
    int b  = blockIdx.x / (BPC * Co);
    for (int i = threadIdx.x; i < Ci * 9; i += TPB)
        ws_w[i] = w[(size_t)co * Ci * 9 + i];
    __syncthreads();
    int nq = W >> 2;
    int r = (blockIdx.x % BPC) * TPB + threadIdx.x;
    if (r >= H * nq) return;
    int q = r % nq, ho = r / nq;
    int wb = q * 4;
    float bv = bias[co];
    float a0 = bv, a1 = bv, a2 = bv, a3 = bv;
    for (int ci = 0; ci < Ci; ++ci) {
        const float* ip = (ci < C1)
            ? in1 + ((size_t)(b * C1 + ci)) * H * W
            : in2 + ((size_t)(b * C2 + (ci - C1))) * H * W;
        const float* wc = ws_w + ci * 9;
#pragma unroll
        for (int kh = 0; kh < 3; ++kh) {
            int y = ho - 1 + kh;
            if (y < 0 || y >= H) continue;
            const float* row = ip + (size_t)y * W + wb;
            float4 xv = *(const float4*)row;
            float xm = (wb > 0) ? row[-1] : 0.f;
            float xp = (wb + 4 < W) ? row[4] : 0.f;
            float w0 = wc[kh * 3], w1 = wc[kh * 3 + 1], w2 = wc[kh * 3 + 2];
            a0 += xm   * w0 + xv.x * w1 + xv.y * w2;
            a1 += xv.x * w0 + xv.y * w1 + xv.z * w2;
            a2 += xv.y * w0 + xv.z * w1 + xv.w * w2;
            a3 += xv.z * w0 + xv.w * w1 + xp   * w2;
        }
    }
    size_t o = ((size_t)(b * Co + co) * H + ho) * W + wb;
    *(float4*)(out + o) = make_float4(fmaxf(a0, 0.f), fmaxf(a1, 0.f), fmaxf(a2, 0.f), fmaxf(a3, 0.f));
}

// ------------- 3x3 conv2d, stride 2, 4 outputs/thread, relu ----------------
__global__ __launch_bounds__(TPB) void conv2d_s2_t4_k(
    const float* __restrict__ in, const float* __restrict__ w,
    const float* __restrict__ bias, float* __restrict__ out,
    int B, int Ci, int Hi, int Wi, int Co, int BPC) {
    __shared__ float ws_w[32 * 9];
    int Ho = Hi >> 1, Wo = Wi >> 1;
    int co = (blockIdx.x / BPC) % Co;
    int b  = blockIdx.x / (BPC * Co);
    for (int i = threadIdx.x; i < Ci * 9; i += TPB)
        ws_w[i] = w[(size_t)co * Ci * 9 + i];
    __syncthreads();
    int nq = Wo >> 2;
    int r = (blockIdx.x % BPC) * TPB + threadIdx.x;
    if (r >= Ho * nq) return;
    int q = r % nq, ho = r / nq;
    int wb = q * 4;
    float bv = bias[co];
    float a0 = bv, a1 = bv, a2 = bv, a3 = bv;
    const float* ipb = in + (size_t)b * Ci * Hi * Wi;
    for (int ci = 0; ci < Ci; ++ci) {
        const float* ip = ipb + (size_t)ci * Hi * Wi;
        const float* wc = ws_w + ci * 9;
#pragma unroll
        for (int kh = 0; kh < 3; ++kh) {
            int y = 2 * ho - 1 + kh;
            if (y < 0 || y >= Hi) continue;
            const float* row = ip + (size_t)y * Wi;
            float z0 = (2 * wb - 1 >= 0) ? row[2 * wb - 1] : 0.f;
            float4 za = *(const float4*)(row + 2 * wb);
            float4 zb = *(const float4*)(row + 2 * wb + 4);
            float w0 = wc[kh * 3], w1 = wc[kh * 3 + 1], w2 = wc[kh * 3 + 2];
            a0 += z0   * w0 + za.x * w1 + za.y * w2;
            a1 += za.y * w0 + za.z * w1 + za.w * w2;
            a2 += za.w * w0 + zb.x * w1 + zb.y * w2;
            a3 += zb.y * w0 + zb.z * w1 + zb.w * w2;
        }
    }
    size_t o = ((size_t)(b * Co + co) * Ho + ho) * Wo + wb;
    *(float4*)(out + o) = make_float4(fmaxf(a0, 0.f), fmaxf(a1, 0.f), fmaxf(a2, 0.f), fmaxf(a3, 0.f));
}

// ------------- transposed conv 4x4 stride 2, 4 outputs/thread, relu --------
__global__ __launch_bounds__(TPB) void convt2d_t4_k(
    const float* __restrict__ in, const float* __restrict__ wt,
    const float* __restrict__ bias, float* __restrict__ out,
    int B, int C, int Hi, int Wi, int BPC) {
    __shared__ float ws_w[32 * 16];
    int Ho = 2 * Hi, Wo = 2 * Wi;
    int co = (blockIdx.x / BPC) % C;
    int b  = blockIdx.x / (BPC * C);
    for (int i = threadIdx.x; i < C * 16; i += TPB) {
        int ci = i >> 4, t = i & 15;
        ws_w[i] = wt[((size_t)ci * C + co) * 16 + t];
    }
    __syncthreads();
    int nq = Wo >> 2;
    int r = (blockIdx.x % BPC) * TPB + threadIdx.x;
    if (r >= Ho * nq) return;
    int q = r % nq, ho = r / nq;
    int wb = q * 4;
    int p = ho & 1;
    int iy0 = (ho + p) / 2 - 1;
    int iy1 = iy0 + 1;
    int ix0 = wb / 2 - 1;
    bool vy0 = (iy0 >= 0) && (iy0 < Hi);
    bool vy1 = (iy1 >= 0) && (iy1 < Hi);
    float bv = bias[co];
    float a0 = bv, a1 = bv, a2 = bv, a3 = bv;
    const float* ipb = in + (size_t)b * C * Hi * Wi;
    for (int ci = 0; ci < C; ++ci) {
        const float* ip = ipb + (size_t)ci * Hi * Wi;
        float u0 = 0, u1 = 0, u2 = 0, u3 = 0, v0 = 0, v1 = 0, v2 = 0, v3 = 0;
        if (vy0) {
            const float* rw = ip + (size_t)iy0 * Wi;
            if (ix0 >= 0) u0 = rw[ix0];
            u1 = rw[ix0 + 1]; u2 = rw[ix0 + 2];
            if (ix0 + 3 < Wi) u3 = rw[ix0 + 3];
        }
        if (vy1) {
            const float* rw = ip + (size_t)iy1 * Wi;
            if (ix0 >= 0) v0 = rw[ix0];
            v1 = rw[ix0 + 1]; v2 = rw[ix0 + 2];
            if (ix0 + 3 < Wi) v3 = rw[ix0 + 3];
        }
        const float* wr0 = ws_w + ci * 16 + (3 - p) * 4;
        const float* wr1 = ws_w + ci * 16 + (1 - p) * 4;
        a0 += u0 * wr0[3] + u1 * wr0[1] + v0 * wr1[3] + v1 * wr1[1];
        a1 += u1 * wr0[2] + u2 * wr0[0] + v1 * wr1[2] + v2 * wr1[0];
        a2 += u1 * wr0[3] + u2 * wr0[1] + v1 * wr1[3] + v2 * wr1[1];
        a3 += u2 * wr0[2] + u3 * wr0[0] + v2 * wr1[2] + v3 * wr1[0];
    }
    size_t o = ((size_t)(b * C + co) * Ho + ho) * Wo + wb;
    *(float4*)(out + o) = make_float4(fmaxf(a0, 0.f), fmaxf(a1, 0.f), fmaxf(a2, 0.f), fmaxf(a3, 0.f));
}

// ---- transpose w_tf3b (co,ci,kd,kh,kw) -> wt[ci][j=kh*3+kw][co][kd] --------
__global__ void transpose_wb_k(const float* __restrict__ wb, float* __restrict__ out) {
    int i = blockIdx.x * TPB + threadIdx.x;
    if (i >= 32 * 9 * 32 * 3) return;
    int kd = i % 3; int t = i / 3;
    int co = t % 32; t /= 32;
    int j  = t % 9;  int ci = t / 9;
    out[i] = wb[(size_t)(co * 32 + ci) * 27 + kd * 9 + j];
}

// ------------- fused 3D branch v2 ------------------------------------------
// grid: B * 2(half) * 400 tiles. block 256 = 64 px (8x8) x 4 groups of 4 co.
// wt: transposed weights [ci][j][co][kd].
__global__ __launch_bounds__(TPB) void conv3d_fused2_k(
    const float* __restrict__ x, const float* __restrict__ wa,
    const float* __restrict__ ba, const float* __restrict__ wt,
    const float* __restrict__ bb, float* __restrict__ out,
    int B, int H, int W) {
    __shared__ float xin[7][12][12];       // 1008
    __shared__ float xa[2][7 * 10 * 10];   // 1400
    __shared__ float wsb[2][9 * 48];       // 864
    int nbx = W / 8, nby = H / 8;
    int blk = blockIdx.x;
    int tile = blk % (nbx * nby);
    int half = (blk / (nbx * nby)) & 1;
    int b = blk / (nbx * nby * 2);
    int bx = tile % nbx, by = tile / nbx;
    int h0 = by * 8, w0 = bx * 8;
    int tid = threadIdx.x;
    int p = tid & 63; int px = p & 7; int py = p >> 3;
    int g = tid >> 6;                       // co group 0..3

    for (int i = tid; i < 7 * 12 * 12; i += TPB) {
        int xx = i % 12; int yy = (i / 12) % 12; int dd = i / 144;
        int gy = h0 - 2 + yy, gx = w0 - 2 + xx;
        float v = 0.f;
        if (gy >= 0 && gy < H && gx >= 0 && gx < W)
            v = x[((size_t)(b * 7 + dd)) * H * W + (size_t)gy * W + gx];
        (&xin[0][0][0])[i] = v;
    }
    float acc[4][7];
#pragma unroll
    for (int r = 0; r < 4; ++r) {
        float bv = bb[half * 16 + g * 4 + r];
#pragma unroll
        for (int d = 0; d < 7; ++d) acc[r][d] = bv;
    }
    __syncthreads();

    // prologue: xa + weights for ci=0 into buffer 0
    {
        const float* wv = wa;  // ci = 0
        for (int i = tid; i < 700; i += TPB) {
            int xx = i % 10; int t2 = i / 10; int yy = t2 % 10; int dd = t2 / 10;
            float a = ba[0];
#pragma unroll
            for (int kd = 0; kd < 3; ++kd) {
                int dz = dd + kd - 1;
                if (dz < 0 || dz >= 7) continue;
#pragma unroll
                for (int kh = 0; kh < 3; ++kh)
#pragma unroll
                    for (int kw = 0; kw < 3; ++kw)
                        a += xin[dz][yy + kh][xx + kw] * wv[kd * 9 + kh * 3 + kw];
            }
            xa[0][i] = fmaxf(a, 0.f);
        }
        for (int i = tid; i < 432; i += TPB) {
            int j = i / 48, t = i % 48;
            wsb[0][j * 48 + t] = wt[(size_t)j * 96 + half * 48 + t];  // ci=0
        }
    }
    __syncthreads();

    for (int ci = 0; ci < 32; ++ci) {
        int cur = ci & 1, nxt = cur ^ 1;
        if (ci + 1 < 32) {
            int cn = ci + 1;
            for (int i = tid; i < 432; i += TPB) {
                int j = i / 48, t = i % 48;
                wsb[nxt][j * 48 + t] = wt[(size_t)cn * 864 + (size_t)j * 96 + half * 48 + t];
            }
            const float* wv = wa + cn * 27;
            float bci = ba[cn];
            for (int i = tid; i < 700; i += TPB) {
                int xx = i % 10; int t2 = i / 10; int yy = t2 % 10; int dd = t2 / 10;
                float a = bci;
#pragma unroll
                for (int kd = 0; kd < 3; ++kd) {
                    int dz = dd + kd - 1;
                    if (dz < 0 || dz >= 7) continue;
#pragma unroll
                    for (int kh = 0; kh < 3; ++kh)
#pragma unroll
                        for (int kw = 0; kw < 3; ++kw)
                            a += xin[dz][yy + kh][xx + kw] * wv[kd * 9 + kh * 3 + kw];
                }
                xa[nxt][i] = fmaxf(a, 0.f);
            }
        }
        // accumulate from buffers [cur]
        const float* xab = xa[cur];
        const float* wb2 = wsb[cur];
        int woff = g * 12;
#pragma unroll
        for (int kh = 0; kh < 3; ++kh) {
#pragma unroll
            for (int kw = 0; kw < 3; ++kw) {
                int j = kh * 3 + kw;
                float xav[7];
#pragma unroll
                for (int d = 0; d < 7; ++d)
                    xav[d] = xab[d * 100 + (py + kh) * 10 + (px + kw)];
                float4 w0 = *(const float4*)(wb2 + j * 48 + woff);
                float4 w1 = *(const float4*)(wb2 + j * 48 + woff + 4);
                float4 w2 = *(const float4*)(wb2 + j * 48 + woff + 8);
                float wr[4][3] = {{w0.x, w0.y, w0.z}, {w0.w, w1.x, w1.y},
                                  {w1.z, w1.w, w2.x}, {w2.y, w2.z, w2.w}};
#pragma unroll
                for (int r = 0; r < 4; ++r) {
#pragma unroll
                    for (int d = 1; d < 7; ++d) acc[r][d] += xav[d - 1] * wr[r][0];
#pragma unroll
                    for (int d = 0; d < 7; ++d) acc[r][d] += xav[d] * wr[r][1];
#pragma unroll
                    for (int d = 0; d < 6; ++d) acc[r][d] += xav[d + 1] * wr[r][2];
                }
            }
        }
        __syncthreads();
    }

    size_t HW = (size_t)H * W;
#pragma unroll
    for (int r = 0; r < 4; ++r) {
        float s = 0.f;
#pragma unroll
        for (int d = 0; d < 7; ++d) s += fmaxf(acc[r][d], 0.f);
        int co = half * 16 + g * 4 + r;
        out[((size_t)(b * 32 + co)) * HW + (size_t)(h0 + py) * W + (w0 + px)] = s * (1.f / 7.f);
    }
}

// ------------- modulated deformable conv, 32 co per thread, 2 halves -------
__global__ __launch_bounds__(TPB) void deform_conv_k(
    const float* __restrict__ x, const float* __restrict__ om,
    const float* __restrict__ w, const float* __restrict__ bias,
    float* __restrict__ out, int B, int H, int W) {
    __shared__ float lwT[63 * 64];
    for (int i = threadIdx.x; i < 63 * 64; i += TPB) {
        int o = i & 63, ck = i >> 6;
        lwT[i] = w[o * 63 + ck];
    }
    __syncthreads();
    int ob = blockIdx.y * 32;
    int idx = blockIdx.x * blockDim.x + threadIdx.x;
    int total = B * H * W;
    if (idx >= total) return;
    int wq = idx % W; int t = idx / W;
    int hq = t % H;   int b = t / H;
    float acc[32];
#pragma unroll
    for (int o = 0; o < 32; ++o) acc[o] = 0.f;
    const size_t HW = (size_t)H * W;
    const float* omb = om + (size_t)b * 189 * HW;
    size_t hw = (size_t)hq * W + wq;
    for (int c = 0; c < 7; ++c) {
        const float* xc = x + ((size_t)(b * 7 + c)) * HW;
#pragma unroll
        for (int k = 0; k < 9; ++k) {
            float dy = omb[(size_t)(c * 18 + k * 2 + 0) * HW + hw];
            float dx = omb[(size_t)(c * 18 + k * 2 + 1) * HW + hw];
            float mv = omb[(size_t)(126 + c * 9 + k) * HW + hw];
            float m = 1.f / (1.f + __expf(-mv));
            float py = (float)hq + (float)(k / 3 - 1) + dy;
            float px = (float)wq + (float)(k % 3 - 1) + dx;
            float y0f = floorf(py), x0f = floorf(px);
            int y0 = (int)y0f, x0 = (int)x0f;
            float wy1 = py - y0f, wx1 = px - x0f;
            float wy0 = 1.f - wy1, wx0 = 1.f - wx1;
            float v00 = 0.f, v01 = 0.f, v10 = 0.f, v11 = 0.f;
            bool yin0 = (y0 >= 0) & (y0 < H);
            bool yin1 = (y0 + 1 >= 0) & (y0 + 1 < H);
            bool xin0 = (x0 >= 0) & (x0 < W);
            bool xin1 = (x0 + 1 >= 0) & (x0 + 1 < W);
            if (yin0) {
                const float* rr = xc + (size_t)y0 * W;
                if (xin0) v00 = rr[x0];
                if (xin1) v01 = rr[x0 + 1];
            }
            if (yin1) {
                const float* rr = xc + (size_t)(y0 + 1) * W;
                if (xin0) v10 = rr[x0];
                if (xin1) v11 = rr[x0 + 1];
            }
            float s = (wy0 * wx0 * v00 + wy0 * wx1 * v01 + wy1 * wx0 * v10 + wy1 * wx1 * v11) * m;
            int ck = c * 9 + k;
            const float* lp = lwT + ck * 64 + ob;
#pragma unroll
            for (int o = 0; o < 32; ++o) acc[o] += s * lp[o];
        }
    }
    size_t obase = (size_t)b * 64 * HW + hw;
#pragma unroll
    for (int o = 0; o < 32; ++o)
        out[obase + (size_t)(ob + o) * HW] = fmaxf(acc[o] + bias[ob + o], 0.f);
}

extern "C" void kernel_launch(void* const* d_in, const int* in_sizes, int n_in,
                              void* d_out, int out_size, void* d_ws, size_t ws_size,
                              hipStream_t stream) {
    (void)in_sizes; (void)n_in; (void)out_size; (void)ws_size;
    const float* inputs = (const float*)d_in[0];
    const float* w_in   = (const float*)d_in[1];  const float* b_in   = (const float*)d_in[2];
    const float* w_dn1a = (const float*)d_in[3];  const float* b_dn1a = (const float*)d_in[4];
    const float* w_dn1b = (const float*)d_in[5];  const float* b_dn1b = (const float*)d_in[6];
    const float* w_up1a = (const float*)d_in[7];  const float* b_up1a = (const float*)d_in[8];
    const float* wt_up1 = (const float*)d_in[9];  const float* bt_up1 = (const float*)d_in[10];
    const float* w_dn2a = (const float*)d_in[11]; const float* b_dn2a = (const float*)d_in[12];
    const float* w_dn2b = (const float*)d_in[13]; const float* b_dn2b = (const float*)d_in[14];
    const float* w_up2a = (const float*)d_in[15]; const float* b_up2a = (const float*)d_in[16];
    const float* wt_up2 = (const float*)d_in[17]; const float* bt_up2 = (const float*)d_in[18];
    const float* w_tra  = (const float*)d_in[19]; const float* b_tra  = (const float*)d_in[20];
    const float* w_trb  = (const float*)d_in[21]; const float* b_trb  = (const float*)d_in[22];
    const float* wt_tr  = (const float*)d_in[23]; const float* bt_tr  = (const float*)d_in[24];
    const float* w_out  = (const float*)d_in[25]; const float* b_out  = (const float*)d_in[26];
    const float* w_tf3a = (const float*)d_in[27]; const float* b_tf3a = (const float*)d_in[28];
    const float* w_tf3b = (const float*)d_in[29]; const float* b_tf3b = (const float*)d_in[30];
    const float* w_tf2  = (const float*)d_in[31]; const float* b_tf2  = (const float*)d_in[32];
    const float* w_om   = (const float*)d_in[33]; const float* b_om   = (const float*)d_in[34];
    const float* w_dc   = (const float*)d_in[35]; const float* b_dc   = (const float*)d_in[36];
    float* out = (float*)d_out;

    const int B = 2, nf = 32, H = 160, W = 160;
    const size_t n160 = (size_t)B * nf * 160 * 160;
    const size_t n80  = (size_t)B * nf * 80 * 80;
    const size_t n40  = (size_t)B * nf * 40 * 40;
    const size_t n20  = (size_t)B * nf * 20 * 20;

    float* ws = (float*)d_ws;
    float* F0    = ws;                 // also MEAN, later OUTC
    float* TMP80 = F0 + n160;
    float* F1    = TMP80 + n80;
    float* TMP40 = F1 + n80;
    float* F2    = TMP40 + n40;
    float* T20A  = F2 + n40;
    float* T20B  = T20A + n20;
    float* T40   = T20B + n20;
    float* T40B  = T40 + n40;
    float* T80   = T40B + n40;
    float* T80B  = T80 + n80;
    float* T160  = T80B + n80;         // U-Net output t
    float* TF    = T160 + n160;        // FUSED
    float* OM    = TF + n160;          // 9,676,800 floats
    float* WT    = OM + (size_t)B * 189 * H * W;  // 27,648 floats

    const int bpc160 = bpc_of(160, 40);   // 25
    const int bpc80  = bpc_of(80, 20);    // 7
    const int bpc40  = bpc_of(40, 10);    // 2
    const int bpc20  = bpc_of(20, 5);     // 1

    // weight transpose for conv3d (tiny)
    transpose_wb_k<<<nblk(32 * 9 * 32 * 3), TPB, 0, stream>>>(w_tf3b, WT);

    // --- 2D U-Net branch ---
    conv2d_c4_k<1, 0><<<B * 8 * bpc160, TPB, 0, stream>>>(inputs, w_in, b_in, nullptr, F0, B, 7, 160, 160, nf, 8, bpc160);
    conv2d_s2_t4_k<<<B * nf * bpc80, TPB, 0, stream>>>(F0, w_dn1a, b_dn1a, TMP80, B, nf, 160, 160, nf, bpc80);
    conv2d_t4_k<1, 0><<<B * nf * bpc80, TPB, 0, stream>>>(TMP80, w_dn1b, b_dn1b, nullptr, F1, B, nf, 80, 80, nf, bpc80);
    conv2d_s2_t4_k<<<B * nf * bpc40, TPB, 0, stream>>>(F1, w_dn2a, b_dn2a, TMP40, B, nf, 80, 80, nf, bpc40);
    conv2d_t4_k<1, 0><<<B * nf * bpc40, TPB, 0, stream>>>(TMP40, w_dn2b, b_dn2b, nullptr, F2, B, nf, 40, 40, nf, bpc40);
    conv2d_s2_t4_k<<<B * nf * bpc20, TPB, 0, stream>>>(F2, w_tra, b_tra, T20A, B, nf, 40, 40, nf, bpc20);
    conv2d_t4_k<1, 0><<<B * nf * bpc20, TPB, 0, stream>>>(T20A, w_trb, b_trb, nullptr, T20B, B, nf, 20, 20, nf, bpc20);
    convt2d_t4_k<<<B * nf * bpc40, TPB, 0, stream>>>(T20B, wt_tr, bt_tr, T40, B, nf, 20, 20, bpc40);
    conv2d_cat_t4_k<<<B * nf * bpc40, TPB, 0, stream>>>(T40, F2, w_up2a, b_up2a, T40B, B, nf, nf, 40, 40, nf, bpc40);
    convt2d_t4_k<<<B * nf * bpc80, TPB, 0, stream>>>(T40B, wt_up2, bt_up2, T80, B, nf, 40, 40, bpc80);
    conv2d_cat_t4_k<<<B * nf * bpc80, TPB, 0, stream>>>(T80, F1, w_up1a, b_up1a, T80B, B, nf, nf, 80, 80, nf, bpc80);
    convt2d_t4_k<<<B * nf * bpc160, TPB, 0, stream>>>(T80B, wt_up1, bt_up1, T160, B, nf, 80, 80, bpc160);

    // --- 3D temporal branch (fused, v2) ---
    conv3d_fused2_k<<<B * 2 * (H / 8) * (W / 8), TPB, 0, stream>>>(inputs, w_tf3a, b_tf3a, WT, b_tf3b, F0, B, H, W);
    // FUSED = relu(conv_tf2(MEAN) + T160)
    conv2d_c4_k<1, 1><<<B * 8 * bpc160, TPB, 0, stream>>>(F0, w_tf2, b_tf2, T160, TF, B, nf, 160, 160, nf, 8, bpc160);

    // --- offset/mask head ---
    conv2d_c4_k<1, 0><<<B * 8 * bpc160, TPB, 0, stream>>>(TF, w_out, b_out, nullptr, F0, B, nf, 160, 160, nf, 8, bpc160);
    conv2d_c4_k<0, 0><<<B * 48 * bpc160, TPB, 0, stream>>>(F0, w_om, b_om, nullptr, OM, B, nf, 160, 160, 189, 48, bpc160);

    // --- deformable conv ---
    dim3 dgrid(nblk((long long)B * H * W), 2);
    deform_conv_k<<<dgrid, TPB, 0, stream>>>(inputs, OM, w_dc, b_dc, out, B, H, W);
}